// Round 1
// 106.937 us; speedup vs baseline: 1.0128x; 1.0128x over previous
//
#include <hip/hip_runtime.h>
#include <math.h>

#define BB 512
#define VV 778
#define FF 1538
#define PP 1024
#define NS 16    // ws slots per batch
#define TPB 512  // threads per block (8 waves)

// ---------- cone field for one (triangle, 3 points) ----------
__device__ __forceinline__ float cone3(const float3 t[3], const float3 p[3]) {
    const float third = 1.0f / 3.0f;
    float cx = (t[0].x + t[1].x + t[2].x) * third;
    float cy = (t[0].y + t[1].y + t[2].y) * third;
    float cz = (t[0].z + t[1].z + t[2].z) * third;
    float e1x = t[1].x - t[0].x, e1y = t[1].y - t[0].y, e1z = t[1].z - t[0].z;
    float e2x = t[2].x - t[0].x, e2y = t[2].y - t[0].y, e2z = t[2].z - t[0].z;
    float nx = e1y * e2z - e1z * e2y;
    float ny = e1z * e2x - e1x * e2z;
    float nz = e1x * e2y - e1y * e2x;
    float inv = 1.0f / (sqrtf(nx * nx + ny * ny + nz * nz) + 1e-9f);
    nx *= inv; ny *= inv; nz *= inv;
    float s = 0.0f;
#pragma unroll
    for (int i = 0; i < 3; i++) {
        float dx = p[i].x - cx, dy = p[i].y - cy, dz = p[i].z - cz;
        float h = dx * nx + dy * ny + dz * nz;
        float r2 = fmaxf(dx * dx + dy * dy + dz * dz - h * h, 0.0f);
        float rl = fmaxf(-h, 0.0f);
        s += rl * expf(-2.0f * r2);   // 2*sigma^2 = 0.5 -> exp(-rho2/0.5)
    }
    return s;
}

// ---------- kernel A: one block per batch ----------
__global__ __launch_bounds__(TPB) void per_batch_kernel(
    const float* __restrict__ verts,   // (2,B,V,3)
    const int*   __restrict__ faces,   // (2,F,3)
    const int*   __restrict__ cidx,    // (B,P,2)
    const float* __restrict__ betas,   // (2,B,10)
    const float* __restrict__ transl,  // (2,B,3)
    const float* __restrict__ j3d,     // (2,B,21,3)
    const float* __restrict__ go,      // (2,B,3)
    const float* __restrict__ pose,    // (2,B,45)
    const float* __restrict__ tgt_trans, // (2,B,3)
    const float* __restrict__ tgt_j3d,   // (2,B,21,3)
    const float* __restrict__ tgt_go,    // (2,B,3)
    const float* __restrict__ tgt_pose,  // (2,B,45)
    const float* __restrict__ tgt_shape, // (2,B,10)
    float* __restrict__ ws)            // (B,16)
{
    // verts as 16B-aligned float4 -> ds_read_b128 gathers; faces table in LDS
    __shared__ float4 sv4[2 * VV];           // 24,896 B
    __shared__ int    sfc[2 * FF * 3];       // 36,912 B
    __shared__ float  red[TPB / 64][NS];     //    512 B
    const int b = blockIdx.x, tid = threadIdx.x;

    // stage both hands' vertices (float3 -> padded float4) for batch b
    const float* v0 = verts + (size_t)b * VV * 3;
    const float* v1 = verts + (size_t)(BB + b) * VV * 3;
    float* svf = (float*)sv4;
    for (int i = tid; i < VV * 3; i += TPB) {
        int v = i / 3, c = i - v * 3;
        svf[(v << 2) + c]          = v0[i];
        svf[((VV + v) << 2) + c]   = v1[i];
    }
    // stage faces table (shared across the batch's pairs)
    for (int i = tid; i < 2 * FF * 3; i += TPB) sfc[i] = faces[i];
    __syncthreads();

    float part[NS];
#pragma unroll
    for (int k = 0; k < NS; k++) part[k] = 0.0f;

    // collision pairs: 1024 / 512 = 2 per thread
    const int2* ci = (const int2*)cidx + (size_t)b * PP;
    for (int p = tid; p < PP; p += TPB) {
        int2 fp = ci[p];
        if (fp.x < 0 || fp.y < 0) continue;
        float3 r[3], q[3];
        {
            int off = (fp.x >= FF) ? VV : 0;
            const int* f = sfc + fp.x * 3;
#pragma unroll
            for (int k = 0; k < 3; k++) {
                float4 w = sv4[f[k] + off];
                r[k] = make_float3(w.x, w.y, w.z);
            }
        }
        {
            int off = (fp.y >= FF) ? VV : 0;
            const int* f = sfc + fp.y * 3;
#pragma unroll
            for (int k = 0; k < 3; k++) {
                float4 w = sv4[f[k] + off];
                q[k] = make_float3(w.x, w.y, w.z);
            }
        }
        part[0] += cone3(r, q) + cone3(q, r);
    }

    // small per-batch loss numerators (raw; masks applied in finalize)
    if (tid < 63) {
        const int t = tid;
        if (t < 10) { float d = betas[b * 10 + t] - betas[(BB + b) * 10 + t]; part[1] = d * d; }
        if (t < 3) {
            float d = (transl[b * 3 + t] - transl[(BB + b) * 3 + t]) -
                      (tgt_trans[b * 3 + t] - tgt_trans[(BB + b) * 3 + t]);
            part[2] = d * d;
        }
        {
            float d = (j3d[b * 63 + t] - j3d[(BB + b) * 63 + t]) -
                      (tgt_j3d[b * 63 + t] - tgt_j3d[(BB + b) * 63 + t]);
            part[3] = d * d;
        }
#pragma unroll
        for (int h = 0; h < 2; h++) {
            const int base = 4 + 6 * h;
            const size_t ob = (size_t)(h * BB + b);
            if (t < 3)  { float d = go[ob * 3 + t] - tgt_go[ob * 3 + t]; part[base + 0] = d * d; }
            if (t < 45) { float d = pose[ob * 45 + t] - tgt_pose[ob * 45 + t]; part[base + 1] = d * d; }
            if (t < 60) {
                int j = 1 + t / 3, c = t % 3;
                float a  = (j3d[ob * 63 + j * 3 + c]     - j3d[ob * 63 + c]) * 1000.0f;
                float b2 = (tgt_j3d[ob * 63 + j * 3 + c] - tgt_j3d[ob * 63 + c]) * 1000.0f;
                part[base + 2] = fabsf(a - b2);
            }
            {
                float a = j3d[ob * 63 + t] * 1000.0f, b2 = tgt_j3d[ob * 63 + t] * 1000.0f;
                part[base + 3] = fabsf(a - b2);
            }
            if (t < 10) { float d = betas[ob * 10 + t] - tgt_shape[ob * 10 + t]; part[base + 4] = d * d; }
            if (t < 3)  { float d = transl[ob * 3 + t] - tgt_trans[ob * 3 + t]; part[base + 5] = fabsf(d); }
        }
    }

    // block reduction: wave shuffle then LDS across the 8 waves
#pragma unroll
    for (int off = 32; off >= 1; off >>= 1) {
#pragma unroll
        for (int k = 0; k < NS; k++) part[k] += __shfl_down(part[k], off);
    }
    const int wave = tid >> 6, lane = tid & 63;
    if (lane == 0) {
#pragma unroll
        for (int k = 0; k < NS; k++) red[wave][k] = part[k];
    }
    __syncthreads();
    if (tid < NS) {
        float s = 0.0f;
#pragma unroll
        for (int w = 0; w < TPB / 64; w++) s += red[w][tid];
        ws[b * NS + tid] = s;
    }
}

// ---------- kernel B: finalize ----------
__global__ __launch_bounds__(256) void finalize_kernel(
    const float* __restrict__ ws,      // (B,16)
    const int*   __restrict__ handed,  // (B,2)
    const int*   __restrict__ validm,  // (2,B)
    const float* __restrict__ logits,  // (B,4)
    const int*   __restrict__ ctgt,    // (B,)
    float* __restrict__ out)           // (12,)
{
    const int tid = threadIdx.x;
    // acc layout: 0 nzsum, 1 nzcnt, 2 shape, 3 transl, 4 j3d, 5 icnt,
    //             6..11 h0 {go,hp,rj,j3,sh,tr}, 12 vcnt0,
    //             13..18 h1 {...}, 19 vcnt1, 20 ce_num, 21 ce_den
    const int NA = 22;
    float acc[22];
#pragma unroll
    for (int k = 0; k < NA; k++) acc[k] = 0.0f;

    for (int b = tid; b < BB; b += 256) {
        const float* w = ws + b * NS;
        float lb = w[0];
        acc[0] += lb;
        acc[1] += (lb != 0.0f) ? 1.0f : 0.0f;
        float inter = ((handed[b * 2] + handed[b * 2 + 1]) == 2) ? 1.0f : 0.0f;
        acc[2] += inter * w[1];
        acc[3] += inter * w[2];
        acc[4] += inter * w[3];
        acc[5] += inter;
#pragma unroll
        for (int h = 0; h < 2; h++) {
            float vm = (float)validm[h * BB + b];
            const int ab = 6 + 7 * h;
#pragma unroll
            for (int k = 0; k < 6; k++) acc[ab + k] += vm * w[4 + 6 * h + k];
            acc[ab + 6] += vm;
        }
        // weighted CE
        float l0 = logits[b * 4 + 0], l1 = logits[b * 4 + 1];
        float l2 = logits[b * 4 + 2], l3 = logits[b * 4 + 3];
        float m = fmaxf(fmaxf(l0, l1), fmaxf(l2, l3));
        float lse = m + logf(expf(l0 - m) + expf(l1 - m) + expf(l2 - m) + expf(l3 - m));
        int t = ctgt[b];
        float lt = (t == 0) ? l0 : (t == 1) ? l1 : (t == 2) ? l2 : l3;
        float nll = lse - lt;
        float cw = (t == 0) ? 1.0f : (t == 3) ? 10.0f : 30.0f;
        float vm = (t != 0) ? 1.0f : 0.0f;
        acc[20] += cw * vm * nll;
        acc[21] += cw * vm;
    }

    // block reduce 22 scalars
#pragma unroll
    for (int off = 32; off >= 1; off >>= 1) {
#pragma unroll
        for (int k = 0; k < NA; k++) acc[k] += __shfl_down(acc[k], off);
    }
    __shared__ float red[4][22];
    const int wave = tid >> 6, lane = tid & 63;
    if (lane == 0) {
#pragma unroll
        for (int k = 0; k < NA; k++) red[wave][k] = acc[k];
    }
    __syncthreads();

    if (tid == 0) {
        float s[22];
#pragma unroll
        for (int k = 0; k < NA; k++)
            s[k] = red[0][k] + red[1][k] + red[2][k] + red[3][k];

        auto idxloss = [](float num, float cnt, float K) -> float {
            float denom = cnt * K;
            return (denom > 0.0f) ? num / fmaxf(denom, 1.0f) : 0.0f;
        };

        out[0] = (s[1] > 0.0f) ? s[0] / fmaxf(s[1], 1.0f) * 100.0f : 0.0f;
        out[1] = idxloss(s[2], s[5], 10.0f);
        out[2] = idxloss(s[3], s[5], 3.0f) * 100.0f;
        out[3] = idxloss(s[4], s[5], 63.0f) * 100.0f;
        out[4] = (idxloss(s[6],  s[12], 3.0f)  + idxloss(s[13], s[19], 3.0f))  * 10.0f;
        out[5] = (idxloss(s[7],  s[12], 45.0f) + idxloss(s[14], s[19], 45.0f)) * 10.0f;
        out[6] = (idxloss(s[8],  s[12], 60.0f) + idxloss(s[15], s[19], 60.0f)) * 0.01f;
        out[7] = (idxloss(s[9],  s[12], 63.0f) + idxloss(s[16], s[19], 63.0f)) * 0.01f;
        out[8] = (idxloss(s[10], s[12], 10.0f) + idxloss(s[17], s[19], 10.0f)) * 10.0f;
        out[9] = (idxloss(s[11], s[12], 3.0f)  + idxloss(s[18], s[19], 3.0f))  * 10.0f;
        out[10] = 0.0f;   // reg: mse(x,x) == 0 identically
        out[11] = s[20] / fmaxf(s[21], 1e-9f);
    }
}

extern "C" void kernel_launch(void* const* d_in, const int* in_sizes, int n_in,
                              void* d_out, int out_size, void* d_ws, size_t ws_size,
                              hipStream_t stream) {
    const float* verts   = (const float*)d_in[0];
    const float* betas   = (const float*)d_in[1];
    const float* transl  = (const float*)d_in[2];
    const float* j3d     = (const float*)d_in[3];
    const float* go      = (const float*)d_in[4];
    const float* pose    = (const float*)d_in[5];
    const float* tt      = (const float*)d_in[6];
    const float* tj      = (const float*)d_in[7];
    const float* tg      = (const float*)d_in[8];
    const float* tp      = (const float*)d_in[9];
    const float* tsh     = (const float*)d_in[10];
    const float* logits  = (const float*)d_in[11];
    const int*   faces   = (const int*)d_in[12];
    const int*   cidx    = (const int*)d_in[13];
    const int*   handed  = (const int*)d_in[14];
    const int*   validm  = (const int*)d_in[15];
    const int*   ctgt    = (const int*)d_in[16];
    float*       ws      = (float*)d_ws;
    float*       out     = (float*)d_out;

    per_batch_kernel<<<BB, TPB, 0, stream>>>(verts, faces, cidx, betas, transl,
                                             j3d, go, pose, tt, tj, tg, tp, tsh, ws);
    finalize_kernel<<<1, 256, 0, stream>>>(ws, handed, validm, logits, ctgt, out);
}

// Round 2
// 105.793 us; speedup vs baseline: 1.0238x; 1.0108x over previous
//
#include <hip/hip_runtime.h>
#include <math.h>

#define BB 512
#define VV 778
#define FF 1538
#define PP 1024
#define NS 16     // ws slots per batch
#define TPB 1024  // one pair per thread

// ---------- cone field for one (triangle, 3 points) ----------
__device__ __forceinline__ float cone3(const float3 t[3], const float3 p[3]) {
    const float third = 1.0f / 3.0f;
    float cx = (t[0].x + t[1].x + t[2].x) * third;
    float cy = (t[0].y + t[1].y + t[2].y) * third;
    float cz = (t[0].z + t[1].z + t[2].z) * third;
    float e1x = t[1].x - t[0].x, e1y = t[1].y - t[0].y, e1z = t[1].z - t[0].z;
    float e2x = t[2].x - t[0].x, e2y = t[2].y - t[0].y, e2z = t[2].z - t[0].z;
    float nx = e1y * e2z - e1z * e2y;
    float ny = e1z * e2x - e1x * e2z;
    float nz = e1x * e2y - e1y * e2x;
    float inv = 1.0f / (sqrtf(nx * nx + ny * ny + nz * nz) + 1e-9f);
    nx *= inv; ny *= inv; nz *= inv;
    float s = 0.0f;
#pragma unroll
    for (int i = 0; i < 3; i++) {
        float dx = p[i].x - cx, dy = p[i].y - cy, dz = p[i].z - cz;
        float h = dx * nx + dy * ny + dz * nz;
        float r2 = fmaxf(dx * dx + dy * dy + dz * dz - h * h, 0.0f);
        float rl = fmaxf(-h, 0.0f);
        s += rl * expf(-2.0f * r2);   // 2*sigma^2 = 0.5 -> exp(-rho2/0.5)
    }
    return s;
}

// ---------- kernel A: one block per batch, one pair per thread ----------
__global__ __launch_bounds__(TPB) void per_batch_kernel(
    const float* __restrict__ verts,   // (2,B,V,3)
    const int*   __restrict__ faces,   // (2,F,3)
    const int*   __restrict__ cidx,    // (B,P,2)
    const float* __restrict__ betas,   // (2,B,10)
    const float* __restrict__ transl,  // (2,B,3)
    const float* __restrict__ j3d,     // (2,B,21,3)
    const float* __restrict__ go,      // (2,B,3)
    const float* __restrict__ pose,    // (2,B,45)
    const float* __restrict__ tgt_trans, // (2,B,3)
    const float* __restrict__ tgt_j3d,   // (2,B,21,3)
    const float* __restrict__ tgt_go,    // (2,B,3)
    const float* __restrict__ tgt_pose,  // (2,B,45)
    const float* __restrict__ tgt_shape, // (2,B,10)
    float* __restrict__ ws)            // (B,16)
{
    __shared__ float4 sv4[2 * VV];       // 24,896 B, float3->float4 padded
    __shared__ int    sfc[2 * FF * 3];   // 36,912 B
    __shared__ float  redc[TPB / 64];    // collision partials per wave
    const int b = blockIdx.x, tid = threadIdx.x;

    // stage both hands' vertices for batch b (float3 -> padded float4)
    const float* v0 = verts + (size_t)b * VV * 3;
    const float* v1 = verts + (size_t)(BB + b) * VV * 3;
    float* svf = (float*)sv4;
    for (int i = tid; i < VV * 3; i += TPB) {
        int v = i / 3, c = i - v * 3;
        svf[(v << 2) + c]        = v0[i];
        svf[((VV + v) << 2) + c] = v1[i];
    }
    // stage faces table
    for (int i = tid; i < 2 * FF * 3; i += TPB) sfc[i] = faces[i];
    __syncthreads();

    // ---- exactly one collision pair per thread ----
    float col = 0.0f;
    {
        int2 fp = ((const int2*)cidx)[(size_t)b * PP + tid];
        if (fp.x >= 0 && fp.y >= 0) {
            float3 r[3], q[3];
            {
                int off = (fp.x >= FF) ? VV : 0;
                const int* f = sfc + fp.x * 3;
#pragma unroll
                for (int k = 0; k < 3; k++) {
                    float4 w = sv4[f[k] + off];
                    r[k] = make_float3(w.x, w.y, w.z);
                }
            }
            {
                int off = (fp.y >= FF) ? VV : 0;
                const int* f = sfc + fp.y * 3;
#pragma unroll
                for (int k = 0; k < 3; k++) {
                    float4 w = sv4[f[k] + off];
                    q[k] = make_float3(w.x, w.y, w.z);
                }
            }
            col = cone3(r, q) + cone3(q, r);
        }
    }
    // block reduction of the single collision scalar
#pragma unroll
    for (int off = 32; off >= 1; off >>= 1) col += __shfl_down(col, off);
    const int wave = tid >> 6, lane = tid & 63;
    if (lane == 0) redc[wave] = col;

    // ---- small per-batch loss numerators: wave 0 only ----
    if (wave == 0) {
        float sm[15];
#pragma unroll
        for (int k = 0; k < 15; k++) sm[k] = 0.0f;
        if (lane < 63) {
            const int t = lane;
            if (t < 10) { float d = betas[b * 10 + t] - betas[(BB + b) * 10 + t]; sm[0] = d * d; }
            if (t < 3) {
                float d = (transl[b * 3 + t] - transl[(BB + b) * 3 + t]) -
                          (tgt_trans[b * 3 + t] - tgt_trans[(BB + b) * 3 + t]);
                sm[1] = d * d;
            }
            {
                float d = (j3d[b * 63 + t] - j3d[(BB + b) * 63 + t]) -
                          (tgt_j3d[b * 63 + t] - tgt_j3d[(BB + b) * 63 + t]);
                sm[2] = d * d;
            }
#pragma unroll
            for (int h = 0; h < 2; h++) {
                const int base = 3 + 6 * h;
                const size_t ob = (size_t)(h * BB + b);
                if (t < 3)  { float d = go[ob * 3 + t] - tgt_go[ob * 3 + t]; sm[base + 0] = d * d; }
                if (t < 45) { float d = pose[ob * 45 + t] - tgt_pose[ob * 45 + t]; sm[base + 1] = d * d; }
                if (t < 60) {
                    int j = 1 + t / 3, c = t % 3;
                    float a  = (j3d[ob * 63 + j * 3 + c]     - j3d[ob * 63 + c]) * 1000.0f;
                    float b2 = (tgt_j3d[ob * 63 + j * 3 + c] - tgt_j3d[ob * 63 + c]) * 1000.0f;
                    sm[base + 2] = fabsf(a - b2);
                }
                {
                    float a = j3d[ob * 63 + t] * 1000.0f, b2 = tgt_j3d[ob * 63 + t] * 1000.0f;
                    sm[base + 3] = fabsf(a - b2);
                }
                if (t < 10) { float d = betas[ob * 10 + t] - tgt_shape[ob * 10 + t]; sm[base + 4] = d * d; }
                if (t < 3)  { float d = transl[ob * 3 + t] - tgt_trans[ob * 3 + t]; sm[base + 5] = fabsf(d); }
            }
        }
        // wave-0 shuffle reduce of the 15 scalars
#pragma unroll
        for (int off = 32; off >= 1; off >>= 1) {
#pragma unroll
            for (int k = 0; k < 15; k++) sm[k] += __shfl_down(sm[k], off);
        }
        if (lane == 0) {
#pragma unroll
            for (int k = 0; k < 15; k++) ws[b * NS + 1 + k] = sm[k];
        }
    }
    __syncthreads();
    if (tid == 0) {
        float s = 0.0f;
#pragma unroll
        for (int w = 0; w < TPB / 64; w++) s += redc[w];
        ws[b * NS] = s;
    }
}

// ---------- kernel B: finalize ----------
__global__ __launch_bounds__(256) void finalize_kernel(
    const float* __restrict__ ws,      // (B,16)
    const int*   __restrict__ handed,  // (B,2)
    const int*   __restrict__ validm,  // (2,B)
    const float* __restrict__ logits,  // (B,4)
    const int*   __restrict__ ctgt,    // (B,)
    float* __restrict__ out)           // (12,)
{
    const int tid = threadIdx.x;
    // acc layout: 0 nzsum, 1 nzcnt, 2 shape, 3 transl, 4 j3d, 5 icnt,
    //             6..11 h0 {go,hp,rj,j3,sh,tr}, 12 vcnt0,
    //             13..18 h1 {...}, 19 vcnt1, 20 ce_num, 21 ce_den
    const int NA = 22;
    float acc[22];
#pragma unroll
    for (int k = 0; k < NA; k++) acc[k] = 0.0f;

    for (int b = tid; b < BB; b += 256) {
        const float* w = ws + b * NS;
        float lb = w[0];
        acc[0] += lb;
        acc[1] += (lb != 0.0f) ? 1.0f : 0.0f;
        float inter = ((handed[b * 2] + handed[b * 2 + 1]) == 2) ? 1.0f : 0.0f;
        acc[2] += inter * w[1];
        acc[3] += inter * w[2];
        acc[4] += inter * w[3];
        acc[5] += inter;
#pragma unroll
        for (int h = 0; h < 2; h++) {
            float vm = (float)validm[h * BB + b];
            const int ab = 6 + 7 * h;
#pragma unroll
            for (int k = 0; k < 6; k++) acc[ab + k] += vm * w[4 + 6 * h + k];
            acc[ab + 6] += vm;
        }
        // weighted CE
        float l0 = logits[b * 4 + 0], l1 = logits[b * 4 + 1];
        float l2 = logits[b * 4 + 2], l3 = logits[b * 4 + 3];
        float m = fmaxf(fmaxf(l0, l1), fmaxf(l2, l3));
        float lse = m + logf(expf(l0 - m) + expf(l1 - m) + expf(l2 - m) + expf(l3 - m));
        int t = ctgt[b];
        float lt = (t == 0) ? l0 : (t == 1) ? l1 : (t == 2) ? l2 : l3;
        float nll = lse - lt;
        float cw = (t == 0) ? 1.0f : (t == 3) ? 10.0f : 30.0f;
        float vm = (t != 0) ? 1.0f : 0.0f;
        acc[20] += cw * vm * nll;
        acc[21] += cw * vm;
    }

    // block reduce 22 scalars
#pragma unroll
    for (int off = 32; off >= 1; off >>= 1) {
#pragma unroll
        for (int k = 0; k < NA; k++) acc[k] += __shfl_down(acc[k], off);
    }
    __shared__ float red[4][22];
    const int wave = tid >> 6, lane = tid & 63;
    if (lane == 0) {
#pragma unroll
        for (int k = 0; k < NA; k++) red[wave][k] = acc[k];
    }
    __syncthreads();

    if (tid == 0) {
        float s[22];
#pragma unroll
        for (int k = 0; k < NA; k++)
            s[k] = red[0][k] + red[1][k] + red[2][k] + red[3][k];

        auto idxloss = [](float num, float cnt, float K) -> float {
            float denom = cnt * K;
            return (denom > 0.0f) ? num / fmaxf(denom, 1.0f) : 0.0f;
        };

        out[0] = (s[1] > 0.0f) ? s[0] / fmaxf(s[1], 1.0f) * 100.0f : 0.0f;
        out[1] = idxloss(s[2], s[5], 10.0f);
        out[2] = idxloss(s[3], s[5], 3.0f) * 100.0f;
        out[3] = idxloss(s[4], s[5], 63.0f) * 100.0f;
        out[4] = (idxloss(s[6],  s[12], 3.0f)  + idxloss(s[13], s[19], 3.0f))  * 10.0f;
        out[5] = (idxloss(s[7],  s[12], 45.0f) + idxloss(s[14], s[19], 45.0f)) * 10.0f;
        out[6] = (idxloss(s[8],  s[12], 60.0f) + idxloss(s[15], s[19], 60.0f)) * 0.01f;
        out[7] = (idxloss(s[9],  s[12], 63.0f) + idxloss(s[16], s[19], 63.0f)) * 0.01f;
        out[8] = (idxloss(s[10], s[12], 10.0f) + idxloss(s[17], s[19], 10.0f)) * 10.0f;
        out[9] = (idxloss(s[11], s[12], 3.0f)  + idxloss(s[18], s[19], 3.0f))  * 10.0f;
        out[10] = 0.0f;   // reg: mse(x,x) == 0 identically
        out[11] = s[20] / fmaxf(s[21], 1e-9f);
    }
}

extern "C" void kernel_launch(void* const* d_in, const int* in_sizes, int n_in,
                              void* d_out, int out_size, void* d_ws, size_t ws_size,
                              hipStream_t stream) {
    const float* verts   = (const float*)d_in[0];
    const float* betas   = (const float*)d_in[1];
    const float* transl  = (const float*)d_in[2];
    const float* j3d     = (const float*)d_in[3];
    const float* go      = (const float*)d_in[4];
    const float* pose    = (const float*)d_in[5];
    const float* tt      = (const float*)d_in[6];
    const float* tj      = (const float*)d_in[7];
    const float* tg      = (const float*)d_in[8];
    const float* tp      = (const float*)d_in[9];
    const float* tsh     = (const float*)d_in[10];
    const float* logits  = (const float*)d_in[11];
    const int*   faces   = (const int*)d_in[12];
    const int*   cidx    = (const int*)d_in[13];
    const int*   handed  = (const int*)d_in[14];
    const int*   validm  = (const int*)d_in[15];
    const int*   ctgt    = (const int*)d_in[16];
    float*       ws      = (float*)d_ws;
    float*       out     = (float*)d_out;

    per_batch_kernel<<<BB, TPB, 0, stream>>>(verts, faces, cidx, betas, transl,
                                             j3d, go, pose, tt, tj, tg, tp, tsh, ws);
    finalize_kernel<<<1, 256, 0, stream>>>(ws, handed, validm, logits, ctgt, out);
}